// Round 15
// baseline (389.123 us; speedup 1.0000x reference)
//
#include <hip/hip_runtime.h>
#include <hip/hip_bf16.h>

#define D_MODEL 1024
#define RANK 64
#define NCOMP 16
#define NKNOW 16384
#define TOPK 8
#define NTOK 8192   // B*S
#define MAXG 48     // candidate-group cap per token (groups of 8 j's)
#define NS 6        // rescore slots per lane (MAXG*8/64)

typedef __attribute__((ext_vector_type(4))) float f32x4;
typedef __attribute__((ext_vector_type(8))) short s16x8;
typedef unsigned short us;

static __device__ __forceinline__ us f2bf(float f) {
  union { float f; unsigned u; } v; v.f = f;
  unsigned r = v.u + 0x7FFFu + ((v.u >> 16) & 1u);
  return (us)(r >> 16);
}
static __device__ __forceinline__ float bf2f(us h) {
  union { unsigned u; float f; } v; v.u = ((unsigned)h) << 16;
  return v.f;
}

// async global->LDS, 16B per lane; LDS dest = wave-uniform base + lane*16.
#define GLOAD16(g, l)                                                        \
  __builtin_amdgcn_global_load_lds(                                          \
      (const __attribute__((address_space(1))) void*)(g),                    \
      (__attribute__((address_space(3))) void*)(l), 16, 0, 0)

// RNE 3-way split: x = h + m + l + r, |r| <= 2^-24 |x|.
#define SPLIT3(f, h, m, l)                                                   \
  do {                                                                       \
    h = f2bf(f);                                                             \
    const float r1_ = (f) - bf2f(h);                                         \
    m = f2bf(r1_);                                                           \
    const float r2_ = r1_ - bf2f(m);                                         \
    l = f2bf(r2_);                                                           \
  } while (0)

// ---------------------------------------------------------------------------
// K1cb3: blocks 0..255: transpose + 3-way RNE-split CN -> Bh,Bm,Bl.
//        blocks 256..1279: Kb = bf16(knowledge_K)  (absorbed k1c).
// ---------------------------------------------------------------------------
__global__ __launch_bounds__(256) void k1cb3(const float* __restrict__ CN,
                                             us* __restrict__ Bh,
                                             us* __restrict__ Bm,
                                             us* __restrict__ Bl,
                                             const float* __restrict__ Kf,
                                             us* __restrict__ Kb) {
  __shared__ float tile[64][65];
  const int tid = threadIdx.x;
  if (blockIdx.x >= 256) {
    const int gid = (blockIdx.x - 256) * 256 + tid;  // one per 4 elems
    f32x4 v = *(const f32x4*)(Kf + (size_t)gid * 4);
    us o0 = f2bf(v[0]), o1 = f2bf(v[1]), o2 = f2bf(v[2]), o3 = f2bf(v[3]);
    unsigned long long pack = (unsigned long long)o0 | ((unsigned long long)o1 << 16)
                            | ((unsigned long long)o2 << 32) | ((unsigned long long)o3 << 48);
    *(unsigned long long*)(Kb + (size_t)gid * 4) = pack;
    return;
  }
  const int n = blockIdx.x >> 4, dt = blockIdx.x & 15;
  {
    const int d = tid >> 2, rc = (tid & 3) * 16;
    const float* p = CN + ((size_t)n * 1024 + dt * 64 + d) * 64 + rc;
#pragma unroll
    for (int e = 0; e < 16; e += 4) {
      const f32x4 v = *(const f32x4*)(p + e);
      tile[d][rc + e]     = v[0];
      tile[d][rc + e + 1] = v[1];
      tile[d][rc + e + 2] = v[2];
      tile[d][rc + e + 3] = v[3];
    }
  }
  __syncthreads();
  {
    const int r = tid >> 2, dc = (tid & 3) * 16;
    s16x8 oh[2], om[2], ol[2];
#pragma unroll
    for (int g = 0; g < 2; g++)
#pragma unroll
      for (int e = 0; e < 8; e++) {
        const float v = tile[dc + g * 8 + e][r];
        us h, m, l;
        SPLIT3(v, h, m, l);
        oh[g][e] = (short)h; om[g][e] = (short)m; ol[g][e] = (short)l;
      }
    const size_t base = (size_t)(n * 64 + r) * 1024 + dt * 64 + dc;
#pragma unroll
    for (int g = 0; g < 2; g++) {
      *(s16x8*)(Bh + base + g * 8) = oh[g];
      *(s16x8*)(Bm + base + g * 8) = om[g];
      *(s16x8*)(Bl + base + g * 8) = ol[g];
    }
  }
}

// ---------------------------------------------------------------------------
// K1m3: T = Xh@Bh + [corrections] with SPLIT ACCUMULATORS (R12-proven,
// NUMERICALLY FROZEN — per-element arithmetic byte-identical to R12/R13/R14).
// R15 adds (bit-identical, schedule-only): XCD-aware block swizzle (8
// row-panels per XCD -> X fetched once per panel, B XCD-local) and
// s_setprio(1) around the MFMA cluster (2 phase-independent blocks/CU).
// ---------------------------------------------------------------------------
__global__ __launch_bounds__(256) void k1m3(const float* __restrict__ X,
                                            const us* __restrict__ Bh,
                                            const us* __restrict__ Bm,
                                            const us* __restrict__ Bl,
                                            float* __restrict__ T) {
  __shared__ us As[3][4][128][8];      // 24 KB [split][kq][row][8]
  __shared__ us Bs[2][3][4][128][8];   // 48 KB [buf][split][kq][col][8]
  const int tid = threadIdx.x;
  const int w = tid >> 6, lane = tid & 63;
  const int wr = w >> 1, wc = w & 1;
  const int l15 = lane & 15, kq = lane >> 4;
  // XCD swizzle: grid 512 = 8 XCDs x 64; xcd gets by in [xcd*8, xcd*8+8)
  const int swz = (blockIdx.x & 7) * 64 + (blockIdx.x >> 3);
  const int by = swz >> 3, bx = swz & 7;
  const int row0 = by * 128, col0 = bx * 128;

  const int sr = tid & 127, sh = tid >> 7;
  const float* xp = X + (size_t)(row0 + sr) * 1024 + sh * 16;

  const us* bsrc0[3]; const us* bsrc1[3];
  int bs_s[3], bs_q[3];
#pragma unroll
  for (int i = 0; i < 3; i++) {
    const int p = w * 3 + i;
    const int s = p >> 2, q = p & 3;
    bs_s[i] = s; bs_q[i] = q;
    const us* base = (s == 0) ? Bh : (s == 1) ? Bm : Bl;
    bsrc0[i] = base + (size_t)(col0 + lane) * 1024 + q * 8;
    bsrc1[i] = base + (size_t)(col0 + 64 + lane) * 1024 + q * 8;
  }

  f32x4 accH[4][4] = {};   // hh product only
  f32x4 accC[4][4] = {};   // correction products
  f32x4 xr[4];
  s16x8 creg[6];

#pragma unroll
  for (int i = 0; i < 3; i++) {
    GLOAD16(bsrc0[i], &Bs[0][bs_s[i]][bs_q[i]][0][0]);
    GLOAD16(bsrc1[i], &Bs[0][bs_s[i]][bs_q[i]][64][0]);
  }
#pragma unroll
  for (int g = 0; g < 4; g++) xr[g] = *(const f32x4*)(xp + g * 4);
#pragma unroll
  for (int g = 0; g < 4; g++)
#pragma unroll
    for (int e = 0; e < 4; e++) {
      us h, m, l;
      SPLIT3(xr[g][e], h, m, l);
      const int c = (g * 4 + e) >> 3, e8 = (g * 4 + e) & 7;
      creg[c][e8] = (short)h; creg[2 + c][e8] = (short)m; creg[4 + c][e8] = (short)l;
    }

  for (int kk = 0; kk < 32; ++kk) {
    const int cur = kk & 1;
    *(s16x8*)&As[0][sh * 2][sr][0]     = creg[0];
    *(s16x8*)&As[0][sh * 2 + 1][sr][0] = creg[1];
    *(s16x8*)&As[1][sh * 2][sr][0]     = creg[2];
    *(s16x8*)&As[1][sh * 2 + 1][sr][0] = creg[3];
    *(s16x8*)&As[2][sh * 2][sr][0]     = creg[4];
    *(s16x8*)&As[2][sh * 2 + 1][sr][0] = creg[5];
    __syncthreads();   // drains B gloads for kk (vmcnt 0) + As writes

    if (kk + 1 < 32) {
      const int ko = (kk + 1) * 32;
#pragma unroll
      for (int i = 0; i < 3; i++) {
        GLOAD16(bsrc0[i] + ko, &Bs[cur ^ 1][bs_s[i]][bs_q[i]][0][0]);
        GLOAD16(bsrc1[i] + ko, &Bs[cur ^ 1][bs_s[i]][bs_q[i]][64][0]);
      }
#pragma unroll
      for (int g = 0; g < 4; g++) xr[g] = *(const f32x4*)(xp + ko + g * 4);
    }

#define PROD(sa, sb, ACC)                                                     \
    do {                                                                      \
      s16x8 af[4];                                                            \
      _Pragma("unroll")                                                       \
      for (int mm = 0; mm < 4; mm++)                                          \
        af[mm] = *(const s16x8*)&As[sa][kq][wr * 64 + mm * 16 + l15][0];      \
      _Pragma("unroll")                                                       \
      for (int nn = 0; nn < 4; nn++) {                                        \
        const s16x8 bfr =                                                     \
            *(const s16x8*)&Bs[cur][sb][kq][wc * 64 + nn * 16 + l15][0];      \
        _Pragma("unroll")                                                     \
        for (int mm = 0; mm < 4; mm++)                                        \
          ACC[mm][nn] = __builtin_amdgcn_mfma_f32_16x16x32_bf16(              \
              af[mm], bfr, ACC[mm][nn], 0, 0, 0);                             \
      }                                                                       \
    } while (0)

    __builtin_amdgcn_s_setprio(1);
    PROD(0, 0, accH);
    PROD(0, 1, accC); PROD(1, 0, accC); PROD(0, 2, accC);
    PROD(2, 0, accC); PROD(1, 1, accC);
    __builtin_amdgcn_s_setprio(0);
#undef PROD

    if (kk + 1 < 32) {
#pragma unroll
      for (int g = 0; g < 4; g++)
#pragma unroll
        for (int e = 0; e < 4; e++) {
          us h, m, l;
          SPLIT3(xr[g][e], h, m, l);
          const int c = (g * 4 + e) >> 3, e8 = (g * 4 + e) & 7;
          creg[c][e8] = (short)h; creg[2 + c][e8] = (short)m;
          creg[4 + c][e8] = (short)l;
        }
    }
    __syncthreads();   // all waves done reading As/Bs[cur]
  }

#pragma unroll
  for (int mm = 0; mm < 4; mm++)
#pragma unroll
    for (int nn = 0; nn < 4; nn++)
#pragma unroll
      for (int r = 0; r < 4; r++)
        T[(size_t)(row0 + wr * 64 + mm * 16 + kq * 4 + r) * 1024
          + col0 + wc * 64 + nn * 16 + l15] = accH[mm][nn][r] + accC[mm][nn][r];
}

// ---------------------------------------------------------------------------
// K1b: Q[tok][r] = sum_n mw[tok][n] * T[tok][n*64+r]; also emit bf16 copy.
// ---------------------------------------------------------------------------
__global__ __launch_bounds__(256) void k1b_weight(const float* __restrict__ T,
                                                  const float* __restrict__ MW,
                                                  float* __restrict__ Qf,
                                                  us* __restrict__ Qb) {
  const int gid = blockIdx.x * 256 + threadIdx.x;  // 0..524287
  const int tok = gid >> 6, r = gid & 63;
  float q = 0.f;
#pragma unroll
  for (int n = 0; n < 16; n++)
    q = fmaf(MW[tok * 16 + n], T[(size_t)tok * 1024 + n * 64 + r], q);
  Qf[gid] = q;
  Qb[gid] = f2bf(q);
}

// ---------------------------------------------------------------------------
// K2s v3 + setprio: dual-j-stream screening (bit-identical GM values).
// ---------------------------------------------------------------------------
__global__ __launch_bounds__(256) void k2s_screen(
    const us* __restrict__ Qb, const us* __restrict__ Kb,
    us* __restrict__ GM) {
  __shared__ us sh[4][32][136];   // 34.8 KB
  const int tid = threadIdx.x;
  const int wv = tid >> 6, lane = tid & 63;
  const int gw = blockIdx.x * 4 + wv;     // 0..4095
  const int tg = gw >> 4;                 // token group 0..255 (32 tokens)
  const int jsl = gw & 15;                // j-slice 0..15
  const int tb = tg * 32;
  const int myTok = lane & 15;
  const int slice = lane >> 4;            // 0..3

  const s16x8 bfa0 = *(const s16x8*)(Qb + (size_t)(tb + myTok) * 64 + slice * 8);
  const s16x8 bfa1 = *(const s16x8*)(Qb + (size_t)(tb + myTok) * 64 + 32 + slice * 8);
  const s16x8 bfb0 = *(const s16x8*)(Qb + (size_t)(tb + 16 + myTok) * 64 + slice * 8);
  const s16x8 bfb1 = *(const s16x8*)(Qb + (size_t)(tb + 16 + myTok) * 64 + 32 + slice * 8);

  const int j0 = jsl * 1024;
  const us* ap0 = Kb + (size_t)(j0 + myTok) * 64 + slice * 8;
  s16x8 afA0 = *(const s16x8*)(ap0);
  s16x8 afA1 = *(const s16x8*)(ap0 + 32);
  s16x8 afB0 = *(const s16x8*)(ap0 + 32 * 1024);
  s16x8 afB1 = *(const s16x8*)(ap0 + 32 * 1024 + 32);
  const bool writer = (slice & 1) == 0;
  const int sub = slice >> 1;

  for (int tt = 0; tt < 32; ++tt) {
    f32x4 ca = {0.f,0.f,0.f,0.f}, cb = ca, cc = ca, cd = ca;
    __builtin_amdgcn_s_setprio(1);
    ca = __builtin_amdgcn_mfma_f32_16x16x32_bf16(afA0, bfa0, ca, 0, 0, 0);
    cb = __builtin_amdgcn_mfma_f32_16x16x32_bf16(afA0, bfb0, cb, 0, 0, 0);
    cc = __builtin_amdgcn_mfma_f32_16x16x32_bf16(afB0, bfa0, cc, 0, 0, 0);
    cd = __builtin_amdgcn_mfma_f32_16x16x32_bf16(afB0, bfb0, cd, 0, 0, 0);
    ca = __builtin_amdgcn_mfma_f32_16x16x32_bf16(afA1, bfa1, ca, 0, 0, 0);
    cb = __builtin_amdgcn_mfma_f32_16x16x32_bf16(afA1, bfb1, cb, 0, 0, 0);
    cc = __builtin_amdgcn_mfma_f32_16x16x32_bf16(afB1, bfa1, cc, 0, 0, 0);
    cd = __builtin_amdgcn_mfma_f32_16x16x32_bf16(afB1, bfb1, cd, 0, 0, 0);
    __builtin_amdgcn_s_setprio(0);
    if (tt + 1 < 32) {
      const us* apA = ap0 + (size_t)(tt + 1) * 1024;
      const us* apB = apA + 32 * 1024;
      afA0 = *(const s16x8*)(apA);
      afA1 = *(const s16x8*)(apA + 32);
      afB0 = *(const s16x8*)(apB);
      afB1 = *(const s16x8*)(apB + 32);
    }
    const float ga4 = fmaxf(fmaxf(ca[0], ca[1]), fmaxf(ca[2], ca[3]));
    const float ga8 = fmaxf(ga4, __shfl_xor(ga4, 16));
    const float gb4 = fmaxf(fmaxf(cb[0], cb[1]), fmaxf(cb[2], cb[3]));
    const float gb8 = fmaxf(gb4, __shfl_xor(gb4, 16));
    const float gc4 = fmaxf(fmaxf(cc[0], cc[1]), fmaxf(cc[2], cc[3]));
    const float gc8 = fmaxf(gc4, __shfl_xor(gc4, 16));
    const float gd4 = fmaxf(fmaxf(cd[0], cd[1]), fmaxf(cd[2], cd[3]));
    const float gd8 = fmaxf(gd4, __shfl_xor(gd4, 16));
    if (writer) {
      sh[wv][myTok][2 * tt + sub]           = f2bf(ga8);
      sh[wv][16 + myTok][2 * tt + sub]      = f2bf(gb8);
      sh[wv][myTok][64 + 2 * tt + sub]      = f2bf(gc8);
      sh[wv][16 + myTok][64 + 2 * tt + sub] = f2bf(gd8);
    }
  }
  __syncthreads();
  {
    const int t = lane >> 1;
    const int half = (lane & 1) * 64;
    us* orow = GM + (size_t)(tb + t) * 2048 + jsl * 128 + half;
#pragma unroll
    for (int ch = 0; ch < 8; ch++)
      *(s16x8*)(orow + ch * 8) = *(const s16x8*)&sh[wv][t][half + ch * 8];
  }
}

// ---------------------------------------------------------------------------
// K2b_sel: one wave per token. 2048 group-maxima -> thr -> compact groups ->
// exact f32 rescore -> exact top-8 (desc score, asc idx) -> softmax ->
// writes out_idx/out_w only.
// ---------------------------------------------------------------------------
__global__ __launch_bounds__(256) void k2b_sel(
    const float* __restrict__ Qf, const float* __restrict__ Kf,
    const us* __restrict__ GM,
    float* __restrict__ out_idx, float* __restrict__ out_w) {
  __shared__ float qsh[4][64];
  __shared__ int csh[4][MAXG];
  __shared__ int scnt[4];
  const int tid = threadIdx.x;
  const int wv = tid >> 6, lane = tid & 63;
  const int tok = blockIdx.x * 4 + wv;    // 0..8191

  if (lane == 0) scnt[wv] = 0;
  qsh[wv][lane] = Qf[(size_t)tok * 64 + lane];

  unsigned long long gv[8];
  const unsigned long long* gmp =
      (const unsigned long long*)(GM + (size_t)tok * 2048);
#pragma unroll
  for (int i = 0; i < 8; i++) gv[i] = gmp[i * 64 + lane];

  float lm = -1e30f;
#pragma unroll
  for (int i = 0; i < 8; i++)
#pragma unroll
    for (int e = 0; e < 4; e++)
      lm = fmaxf(lm, bf2f((us)(gv[i] >> (e * 16))));

  float v = lm, m8 = -1e30f;
#pragma unroll
  for (int e = 0; e < 8; e++) {
    float m = v;
#pragma unroll
    for (int d = 1; d < 64; d <<= 1) m = fmaxf(m, __shfl_xor(m, d));
    m8 = m;
    if (e < 7) v = (v == m) ? -1e30f : v;
  }
  const float thr = m8 - 0.04f;

#pragma unroll
  for (int i = 0; i < 8; i++) {
#pragma unroll
    for (int e = 0; e < 4; e++) {
      const float g = bf2f((us)(gv[i] >> (e * 16)));
      if (g >= thr) {
        const int s = atomicAdd(&scnt[wv], 1);
        if (s < MAXG) csh[wv][s] = i * 256 + lane * 4 + e;
      }
    }
  }
  int ng = scnt[wv];
  if (ng > MAXG) ng = MAXG;
  const int nj = ng * 8;

  float scR[NS]; int jR[NS];
#pragma unroll
  for (int s = 0; s < NS; s++) {
    scR[s] = -1e30f; jR[s] = 0x7fffffff;
    if (s * 64 < nj) {
      const int ci = s * 64 + lane;
      if (ci < nj) {
        const int j = csh[wv][ci >> 3] * 8 + (ci & 7);
        const float* kp = Kf + (size_t)j * 64;
        float acc = 0.f;
#pragma unroll
        for (int k = 0; k < 64; k += 4) {
          const f32x4 qv = *(const f32x4*)&qsh[wv][k];
          const f32x4 kv = *(const f32x4*)(kp + k);
          acc = fmaf(qv[0], kv[0], acc);
          acc = fmaf(qv[1], kv[1], acc);
          acc = fmaf(qv[2], kv[2], acc);
          acc = fmaf(qv[3], kv[3], acc);
        }
        scR[s] = acc * 0.125f; jR[s] = j;
      }
    }
  }

  float wsv[8]; int wjv[8];
#pragma unroll
  for (int e = 0; e < 8; e++) {
    float ms = scR[0]; int mj = jR[0];
#pragma unroll
    for (int s = 1; s < NS; s++)
      if (scR[s] > ms || (scR[s] == ms && jR[s] < mj)) { ms = scR[s]; mj = jR[s]; }
#pragma unroll
    for (int d = 1; d < 64; d <<= 1) {
      const float rs = __shfl_xor(ms, d);
      const int rj = __shfl_xor(mj, d);
      if (rs > ms || (rs == ms && rj < mj)) { ms = rs; mj = rj; }
    }
    wsv[e] = ms; wjv[e] = mj;
#pragma unroll
    for (int s = 0; s < NS; s++)
      if (jR[s] == mj) { scR[s] = -1e30f; jR[s] = 0x7fffffff; }
  }

  const float m0 = wsv[0];
  float ex[8], sum = 0.f;
#pragma unroll
  for (int r = 0; r < 8; r++) { ex[r] = expf(wsv[r] - m0); sum += ex[r]; }
  const float inv = 1.f / sum;

  if (lane == 0) {
#pragma unroll
    for (int r = 0; r < 8; r++) {
      out_idx[(size_t)tok * 8 + r] = (float)wjv[r];
      out_w[(size_t)tok * 8 + r] = ex[r] * inv;
    }
  }
}

// ---------------------------------------------------------------------------
// K2g: V-gather. One wave per token.
// ---------------------------------------------------------------------------
__global__ __launch_bounds__(256) void k2g_gather(
    const float* __restrict__ V, const float* __restrict__ out_idx,
    const float* __restrict__ out_w, float* __restrict__ out) {
  const int tid = threadIdx.x;
  const int wv = tid >> 6, lane = tid & 63;
  const int tok = blockIdx.x * 4 + wv;    // 0..8191

  int jv[8]; float wv8[8];
#pragma unroll
  for (int r = 0; r < 8; r++) {
    jv[r] = ((int)out_idx[(size_t)tok * 8 + r]) & (NKNOW - 1);
    wv8[r] = out_w[(size_t)tok * 8 + r];
  }

  f32x4 a0 = {0.f,0.f,0.f,0.f}, a1 = a0, a2 = a0, a3 = a0;
#pragma unroll
  for (int r = 0; r < 8; r++) {
    const float w = wv8[r];
    const float* vp = V + (size_t)jv[r] * 1024 + lane * 16;
    const f32x4 v0 = *(const f32x4*)(vp);
    const f32x4 v1 = *(const f32x4*)(vp + 4);
    const f32x4 v2 = *(const f32x4*)(vp + 8);
    const f32x4 v3 = *(const f32x4*)(vp + 12);
    a0 += w * v0; a1 += w * v1; a2 += w * v2; a3 += w * v3;
  }
  float* op = out + (size_t)tok * 1024 + lane * 16;
  *(f32x4*)(op)      = a0;
  *(f32x4*)(op + 4)  = a1;
  *(f32x4*)(op + 8)  = a2;
  *(f32x4*)(op + 12) = a3;
}

// ---------------------------------------------------------------------------
extern "C" void kernel_launch(void* const* d_in, const int* in_sizes, int n_in,
                              void* d_out, int out_size, void* d_ws, size_t ws_size,
                              hipStream_t stream) {
  const float* x  = (const float*)d_in[0];   // [2,4096,1024]
  const float* mw = (const float*)d_in[1];   // [2,4096,16]
  const float* cn = (const float*)d_in[2];   // [16,1024,64]
  const float* kK = (const float*)d_in[3];   // [16384,64]
  const float* kV = (const float*)d_in[4];   // [16384,1024]

  float* out  = (float*)d_out;               // 8192*1024
  float* oidx = out + (size_t)NTOK * D_MODEL;       // 8192*8
  float* ow   = oidx + (size_t)NTOK * TOPK;         // 8192*8

  // Workspace (43 MB, well under the 72.35 MB proven in R5):
  //  [0,32M)      T (k1m3 out, k1b in); GM overlays after k1b.
  //  [32M,34M)    Qf   [34M,35M) Qb   [35M,37M) Kb
  //  [37M,39M)    Bh   [39M,41M) Bm   [41M,43M) Bl
  float* T   = (float*)d_ws;
  us* GM     = (us*)d_ws;
  float* Qf  = (float*)((char*)d_ws + 33554432);
  us* Qb     = (us*)((char*)d_ws + 35651584);
  us* Kb     = (us*)((char*)d_ws + 36700160);
  us* Bh     = (us*)((char*)d_ws + 38797312);
  us* Bm     = (us*)((char*)d_ws + 40894464);
  us* Bl     = (us*)((char*)d_ws + 42991616);

  k1cb3<<<1280, 256, 0, stream>>>(cn, Bh, Bm, Bl, kK, Kb);
  k1m3<<<512, 256, 0, stream>>>(x, Bh, Bm, Bl, T);
  k1b_weight<<<2048, 256, 0, stream>>>(T, mw, Qf, Qb);
  k2s_screen<<<1024, 256, 0, stream>>>(Qb, Kb, GM);
  k2b_sel<<<2048, 256, 0, stream>>>(Qf, kK, GM, oidx, ow);
  k2g_gather<<<2048, 256, 0, stream>>>(kV, oidx, ow, out);

  (void)in_sizes; (void)n_in; (void)out_size; (void)ws_size;
}

// Round 16
// 301.275 us; speedup vs baseline: 1.2916x; 1.2916x over previous
//
#include <hip/hip_runtime.h>
#include <hip/hip_bf16.h>

#define D_MODEL 1024
#define RANK 64
#define NCOMP 16
#define NKNOW 16384
#define TOPK 8
#define NTOK 8192   // B*S
#define MAXG 48     // candidate-group cap per token (groups of 8 j's)
#define NS 6        // rescore slots per lane (MAXG*8/64)

typedef __attribute__((ext_vector_type(4))) float f32x4;
typedef __attribute__((ext_vector_type(8))) short s16x8;
typedef unsigned short us;

static __device__ __forceinline__ us f2bf(float f) {
  union { float f; unsigned u; } v; v.f = f;
  unsigned r = v.u + 0x7FFFu + ((v.u >> 16) & 1u);
  return (us)(r >> 16);
}
static __device__ __forceinline__ float bf2f(us h) {
  union { unsigned u; float f; } v; v.u = ((unsigned)h) << 16;
  return v.f;
}

// async global->LDS, 16B per lane; LDS dest = wave-uniform base + lane*16.
#define GLOAD16(g, l)                                                        \
  __builtin_amdgcn_global_load_lds(                                          \
      (const __attribute__((address_space(1))) void*)(g),                    \
      (__attribute__((address_space(3))) void*)(l), 16, 0, 0)

// RNE 3-way split: x = h + m + l + r, |r| <= 2^-24 |x|.
#define SPLIT3(f, h, m, l)                                                   \
  do {                                                                       \
    h = f2bf(f);                                                             \
    const float r1_ = (f) - bf2f(h);                                         \
    m = f2bf(r1_);                                                           \
    const float r2_ = r1_ - bf2f(m);                                         \
    l = f2bf(r2_);                                                           \
  } while (0)

// ---------------------------------------------------------------------------
// K1cb3: blocks 0..255: transpose + 3-way RNE-split CN -> Bh,Bm,Bl.
//        blocks 256..1279: Kb = bf16(knowledge_K)  (absorbed k1c).
// ---------------------------------------------------------------------------
__global__ __launch_bounds__(256) void k1cb3(const float* __restrict__ CN,
                                             us* __restrict__ Bh,
                                             us* __restrict__ Bm,
                                             us* __restrict__ Bl,
                                             const float* __restrict__ Kf,
                                             us* __restrict__ Kb) {
  __shared__ float tile[64][65];
  const int tid = threadIdx.x;
  if (blockIdx.x >= 256) {
    const int gid = (blockIdx.x - 256) * 256 + tid;  // one per 4 elems
    f32x4 v = *(const f32x4*)(Kf + (size_t)gid * 4);
    us o0 = f2bf(v[0]), o1 = f2bf(v[1]), o2 = f2bf(v[2]), o3 = f2bf(v[3]);
    unsigned long long pack = (unsigned long long)o0 | ((unsigned long long)o1 << 16)
                            | ((unsigned long long)o2 << 32) | ((unsigned long long)o3 << 48);
    *(unsigned long long*)(Kb + (size_t)gid * 4) = pack;
    return;
  }
  const int n = blockIdx.x >> 4, dt = blockIdx.x & 15;
  {
    const int d = tid >> 2, rc = (tid & 3) * 16;
    const float* p = CN + ((size_t)n * 1024 + dt * 64 + d) * 64 + rc;
#pragma unroll
    for (int e = 0; e < 16; e += 4) {
      const f32x4 v = *(const f32x4*)(p + e);
      tile[d][rc + e]     = v[0];
      tile[d][rc + e + 1] = v[1];
      tile[d][rc + e + 2] = v[2];
      tile[d][rc + e + 3] = v[3];
    }
  }
  __syncthreads();
  {
    const int r = tid >> 2, dc = (tid & 3) * 16;
    s16x8 oh[2], om[2], ol[2];
#pragma unroll
    for (int g = 0; g < 2; g++)
#pragma unroll
      for (int e = 0; e < 8; e++) {
        const float v = tile[dc + g * 8 + e][r];
        us h, m, l;
        SPLIT3(v, h, m, l);
        oh[g][e] = (short)h; om[g][e] = (short)m; ol[g][e] = (short)l;
      }
    const size_t base = (size_t)(n * 64 + r) * 1024 + dt * 64 + dc;
#pragma unroll
    for (int g = 0; g < 2; g++) {
      *(s16x8*)(Bh + base + g * 8) = oh[g];
      *(s16x8*)(Bm + base + g * 8) = om[g];
      *(s16x8*)(Bl + base + g * 8) = ol[g];
    }
  }
}

// ---------------------------------------------------------------------------
// K1m3: T = Xh@Bh + [corrections] with SPLIT ACCUMULATORS (R12-proven,
// NUMERICALLY FROZEN — per-element arithmetic byte-identical to R12-R15).
// R16: R14 body verbatim (VGPR 128 proven; NO setprio — R15 showed it
// inflates VGPR past the 256-sum wall) + XCD swizzle only (R15-confirmed
// FETCH_SIZE halving, 3 dead-after-prologue index ops).
// ---------------------------------------------------------------------------
__global__ __launch_bounds__(256) void k1m3(const float* __restrict__ X,
                                            const us* __restrict__ Bh,
                                            const us* __restrict__ Bm,
                                            const us* __restrict__ Bl,
                                            float* __restrict__ T) {
  __shared__ us As[3][4][128][8];      // 24 KB [split][kq][row][8]
  __shared__ us Bs[2][3][4][128][8];   // 48 KB [buf][split][kq][col][8]
  const int tid = threadIdx.x;
  const int w = tid >> 6, lane = tid & 63;
  const int wr = w >> 1, wc = w & 1;
  const int l15 = lane & 15, kq = lane >> 4;
  // XCD swizzle: grid 512 = 8 XCDs x 64; xcd gets by in [xcd*8, xcd*8+8)
  const int swz = (blockIdx.x & 7) * 64 + (blockIdx.x >> 3);
  const int by = swz >> 3, bx = swz & 7;
  const int row0 = by * 128, col0 = bx * 128;

  const int sr = tid & 127, sh = tid >> 7;
  const float* xp = X + (size_t)(row0 + sr) * 1024 + sh * 16;

  const us* bsrc0[3]; const us* bsrc1[3];
  int bs_s[3], bs_q[3];
#pragma unroll
  for (int i = 0; i < 3; i++) {
    const int p = w * 3 + i;
    const int s = p >> 2, q = p & 3;
    bs_s[i] = s; bs_q[i] = q;
    const us* base = (s == 0) ? Bh : (s == 1) ? Bm : Bl;
    bsrc0[i] = base + (size_t)(col0 + lane) * 1024 + q * 8;
    bsrc1[i] = base + (size_t)(col0 + 64 + lane) * 1024 + q * 8;
  }

  f32x4 accH[4][4] = {};   // hh product only
  f32x4 accC[4][4] = {};   // correction products
  f32x4 xr[4];
  s16x8 creg[6];

#pragma unroll
  for (int i = 0; i < 3; i++) {
    GLOAD16(bsrc0[i], &Bs[0][bs_s[i]][bs_q[i]][0][0]);
    GLOAD16(bsrc1[i], &Bs[0][bs_s[i]][bs_q[i]][64][0]);
  }
#pragma unroll
  for (int g = 0; g < 4; g++) xr[g] = *(const f32x4*)(xp + g * 4);
#pragma unroll
  for (int g = 0; g < 4; g++)
#pragma unroll
    for (int e = 0; e < 4; e++) {
      us h, m, l;
      SPLIT3(xr[g][e], h, m, l);
      const int c = (g * 4 + e) >> 3, e8 = (g * 4 + e) & 7;
      creg[c][e8] = (short)h; creg[2 + c][e8] = (short)m; creg[4 + c][e8] = (short)l;
    }

  for (int kk = 0; kk < 32; ++kk) {
    const int cur = kk & 1;
    *(s16x8*)&As[0][sh * 2][sr][0]     = creg[0];
    *(s16x8*)&As[0][sh * 2 + 1][sr][0] = creg[1];
    *(s16x8*)&As[1][sh * 2][sr][0]     = creg[2];
    *(s16x8*)&As[1][sh * 2 + 1][sr][0] = creg[3];
    *(s16x8*)&As[2][sh * 2][sr][0]     = creg[4];
    *(s16x8*)&As[2][sh * 2 + 1][sr][0] = creg[5];
    __syncthreads();   // drains B gloads for kk (vmcnt 0) + As writes

    if (kk + 1 < 32) {
      const int ko = (kk + 1) * 32;
#pragma unroll
      for (int i = 0; i < 3; i++) {
        GLOAD16(bsrc0[i] + ko, &Bs[cur ^ 1][bs_s[i]][bs_q[i]][0][0]);
        GLOAD16(bsrc1[i] + ko, &Bs[cur ^ 1][bs_s[i]][bs_q[i]][64][0]);
      }
#pragma unroll
      for (int g = 0; g < 4; g++) xr[g] = *(const f32x4*)(xp + ko + g * 4);
    }

#define PROD(sa, sb, ACC)                                                     \
    do {                                                                      \
      s16x8 af[4];                                                            \
      _Pragma("unroll")                                                       \
      for (int mm = 0; mm < 4; mm++)                                          \
        af[mm] = *(const s16x8*)&As[sa][kq][wr * 64 + mm * 16 + l15][0];      \
      _Pragma("unroll")                                                       \
      for (int nn = 0; nn < 4; nn++) {                                        \
        const s16x8 bfr =                                                     \
            *(const s16x8*)&Bs[cur][sb][kq][wc * 64 + nn * 16 + l15][0];      \
        _Pragma("unroll")                                                     \
        for (int mm = 0; mm < 4; mm++)                                        \
          ACC[mm][nn] = __builtin_amdgcn_mfma_f32_16x16x32_bf16(              \
              af[mm], bfr, ACC[mm][nn], 0, 0, 0);                             \
      }                                                                       \
    } while (0)

    PROD(0, 0, accH);
    PROD(0, 1, accC); PROD(1, 0, accC); PROD(0, 2, accC);
    PROD(2, 0, accC); PROD(1, 1, accC);
#undef PROD

    if (kk + 1 < 32) {
#pragma unroll
      for (int g = 0; g < 4; g++)
#pragma unroll
        for (int e = 0; e < 4; e++) {
          us h, m, l;
          SPLIT3(xr[g][e], h, m, l);
          const int c = (g * 4 + e) >> 3, e8 = (g * 4 + e) & 7;
          creg[c][e8] = (short)h; creg[2 + c][e8] = (short)m;
          creg[4 + c][e8] = (short)l;
        }
    }
    __syncthreads();   // all waves done reading As/Bs[cur]
  }

#pragma unroll
  for (int mm = 0; mm < 4; mm++)
#pragma unroll
    for (int nn = 0; nn < 4; nn++)
#pragma unroll
      for (int r = 0; r < 4; r++)
        T[(size_t)(row0 + wr * 64 + mm * 16 + kq * 4 + r) * 1024
          + col0 + wc * 64 + nn * 16 + l15] = accH[mm][nn][r] + accC[mm][nn][r];
}

// ---------------------------------------------------------------------------
// K1b: Q[tok][r] = sum_n mw[tok][n] * T[tok][n*64+r]; also emit bf16 copy.
// ---------------------------------------------------------------------------
__global__ __launch_bounds__(256) void k1b_weight(const float* __restrict__ T,
                                                  const float* __restrict__ MW,
                                                  float* __restrict__ Qf,
                                                  us* __restrict__ Qb) {
  const int gid = blockIdx.x * 256 + threadIdx.x;  // 0..524287
  const int tok = gid >> 6, r = gid & 63;
  float q = 0.f;
#pragma unroll
  for (int n = 0; n < 16; n++)
    q = fmaf(MW[tok * 16 + n], T[(size_t)tok * 1024 + n * 64 + r], q);
  Qf[gid] = q;
  Qb[gid] = f2bf(q);
}

// ---------------------------------------------------------------------------
// K2s v3 (R14 verbatim, no setprio): dual-j-stream screening, 2 token
// groups per wave. GM values bit-identical.
// ---------------------------------------------------------------------------
__global__ __launch_bounds__(256) void k2s_screen(
    const us* __restrict__ Qb, const us* __restrict__ Kb,
    us* __restrict__ GM) {
  __shared__ us sh[4][32][136];   // 34.8 KB
  const int tid = threadIdx.x;
  const int wv = tid >> 6, lane = tid & 63;
  const int gw = blockIdx.x * 4 + wv;     // 0..4095
  const int tg = gw >> 4;                 // token group 0..255 (32 tokens)
  const int jsl = gw & 15;                // j-slice 0..15
  const int tb = tg * 32;
  const int myTok = lane & 15;
  const int slice = lane >> 4;            // 0..3

  const s16x8 bfa0 = *(const s16x8*)(Qb + (size_t)(tb + myTok) * 64 + slice * 8);
  const s16x8 bfa1 = *(const s16x8*)(Qb + (size_t)(tb + myTok) * 64 + 32 + slice * 8);
  const s16x8 bfb0 = *(const s16x8*)(Qb + (size_t)(tb + 16 + myTok) * 64 + slice * 8);
  const s16x8 bfb1 = *(const s16x8*)(Qb + (size_t)(tb + 16 + myTok) * 64 + 32 + slice * 8);

  const int j0 = jsl * 1024;
  const us* ap0 = Kb + (size_t)(j0 + myTok) * 64 + slice * 8;
  s16x8 afA0 = *(const s16x8*)(ap0);
  s16x8 afA1 = *(const s16x8*)(ap0 + 32);
  s16x8 afB0 = *(const s16x8*)(ap0 + 32 * 1024);
  s16x8 afB1 = *(const s16x8*)(ap0 + 32 * 1024 + 32);
  const bool writer = (slice & 1) == 0;
  const int sub = slice >> 1;

  for (int tt = 0; tt < 32; ++tt) {
    f32x4 ca = {0.f,0.f,0.f,0.f}, cb = ca, cc = ca, cd = ca;
    ca = __builtin_amdgcn_mfma_f32_16x16x32_bf16(afA0, bfa0, ca, 0, 0, 0);
    cb = __builtin_amdgcn_mfma_f32_16x16x32_bf16(afA0, bfb0, cb, 0, 0, 0);
    cc = __builtin_amdgcn_mfma_f32_16x16x32_bf16(afB0, bfa0, cc, 0, 0, 0);
    cd = __builtin_amdgcn_mfma_f32_16x16x32_bf16(afB0, bfb0, cd, 0, 0, 0);
    ca = __builtin_amdgcn_mfma_f32_16x16x32_bf16(afA1, bfa1, ca, 0, 0, 0);
    cb = __builtin_amdgcn_mfma_f32_16x16x32_bf16(afA1, bfb1, cb, 0, 0, 0);
    cc = __builtin_amdgcn_mfma_f32_16x16x32_bf16(afB1, bfa1, cc, 0, 0, 0);
    cd = __builtin_amdgcn_mfma_f32_16x16x32_bf16(afB1, bfb1, cd, 0, 0, 0);
    if (tt + 1 < 32) {
      const us* apA = ap0 + (size_t)(tt + 1) * 1024;
      const us* apB = apA + 32 * 1024;
      afA0 = *(const s16x8*)(apA);
      afA1 = *(const s16x8*)(apA + 32);
      afB0 = *(const s16x8*)(apB);
      afB1 = *(const s16x8*)(apB + 32);
    }
    const float ga4 = fmaxf(fmaxf(ca[0], ca[1]), fmaxf(ca[2], ca[3]));
    const float ga8 = fmaxf(ga4, __shfl_xor(ga4, 16));
    const float gb4 = fmaxf(fmaxf(cb[0], cb[1]), fmaxf(cb[2], cb[3]));
    const float gb8 = fmaxf(gb4, __shfl_xor(gb4, 16));
    const float gc4 = fmaxf(fmaxf(cc[0], cc[1]), fmaxf(cc[2], cc[3]));
    const float gc8 = fmaxf(gc4, __shfl_xor(gc4, 16));
    const float gd4 = fmaxf(fmaxf(cd[0], cd[1]), fmaxf(cd[2], cd[3]));
    const float gd8 = fmaxf(gd4, __shfl_xor(gd4, 16));
    if (writer) {
      sh[wv][myTok][2 * tt + sub]           = f2bf(ga8);
      sh[wv][16 + myTok][2 * tt + sub]      = f2bf(gb8);
      sh[wv][myTok][64 + 2 * tt + sub]      = f2bf(gc8);
      sh[wv][16 + myTok][64 + 2 * tt + sub] = f2bf(gd8);
    }
  }
  __syncthreads();
  {
    const int t = lane >> 1;
    const int half = (lane & 1) * 64;
    us* orow = GM + (size_t)(tb + t) * 2048 + jsl * 128 + half;
#pragma unroll
    for (int ch = 0; ch < 8; ch++)
      *(s16x8*)(orow + ch * 8) = *(const s16x8*)&sh[wv][t][half + ch * 8];
  }
}

// ---------------------------------------------------------------------------
// K2b_sel: one wave per token. 2048 group-maxima -> thr -> compact groups ->
// exact f32 rescore -> exact top-8 (desc score, asc idx) -> softmax ->
// writes out_idx/out_w only.
// ---------------------------------------------------------------------------
__global__ __launch_bounds__(256) void k2b_sel(
    const float* __restrict__ Qf, const float* __restrict__ Kf,
    const us* __restrict__ GM,
    float* __restrict__ out_idx, float* __restrict__ out_w) {
  __shared__ float qsh[4][64];
  __shared__ int csh[4][MAXG];
  __shared__ int scnt[4];
  const int tid = threadIdx.x;
  const int wv = tid >> 6, lane = tid & 63;
  const int tok = blockIdx.x * 4 + wv;    // 0..8191

  if (lane == 0) scnt[wv] = 0;
  qsh[wv][lane] = Qf[(size_t)tok * 64 + lane];

  unsigned long long gv[8];
  const unsigned long long* gmp =
      (const unsigned long long*)(GM + (size_t)tok * 2048);
#pragma unroll
  for (int i = 0; i < 8; i++) gv[i] = gmp[i * 64 + lane];

  float lm = -1e30f;
#pragma unroll
  for (int i = 0; i < 8; i++)
#pragma unroll
    for (int e = 0; e < 4; e++)
      lm = fmaxf(lm, bf2f((us)(gv[i] >> (e * 16))));

  float v = lm, m8 = -1e30f;
#pragma unroll
  for (int e = 0; e < 8; e++) {
    float m = v;
#pragma unroll
    for (int d = 1; d < 64; d <<= 1) m = fmaxf(m, __shfl_xor(m, d));
    m8 = m;
    if (e < 7) v = (v == m) ? -1e30f : v;
  }
  const float thr = m8 - 0.04f;

#pragma unroll
  for (int i = 0; i < 8; i++) {
#pragma unroll
    for (int e = 0; e < 4; e++) {
      const float g = bf2f((us)(gv[i] >> (e * 16)));
      if (g >= thr) {
        const int s = atomicAdd(&scnt[wv], 1);
        if (s < MAXG) csh[wv][s] = i * 256 + lane * 4 + e;
      }
    }
  }
  int ng = scnt[wv];
  if (ng > MAXG) ng = MAXG;
  const int nj = ng * 8;

  float scR[NS]; int jR[NS];
#pragma unroll
  for (int s = 0; s < NS; s++) {
    scR[s] = -1e30f; jR[s] = 0x7fffffff;
    if (s * 64 < nj) {
      const int ci = s * 64 + lane;
      if (ci < nj) {
        const int j = csh[wv][ci >> 3] * 8 + (ci & 7);
        const float* kp = Kf + (size_t)j * 64;
        float acc = 0.f;
#pragma unroll
        for (int k = 0; k < 64; k += 4) {
          const f32x4 qv = *(const f32x4*)&qsh[wv][k];
          const f32x4 kv = *(const f32x4*)(kp + k);
          acc = fmaf(qv[0], kv[0], acc);
          acc = fmaf(qv[1], kv[1], acc);
          acc = fmaf(qv[2], kv[2], acc);
          acc = fmaf(qv[3], kv[3], acc);
        }
        scR[s] = acc * 0.125f; jR[s] = j;
      }
    }
  }

  float wsv[8]; int wjv[8];
#pragma unroll
  for (int e = 0; e < 8; e++) {
    float ms = scR[0]; int mj = jR[0];
#pragma unroll
    for (int s = 1; s < NS; s++)
      if (scR[s] > ms || (scR[s] == ms && jR[s] < mj)) { ms = scR[s]; mj = jR[s]; }
#pragma unroll
    for (int d = 1; d < 64; d <<= 1) {
      const float rs = __shfl_xor(ms, d);
      const int rj = __shfl_xor(mj, d);
      if (rs > ms || (rs == ms && rj < mj)) { ms = rs; mj = rj; }
    }
    wsv[e] = ms; wjv[e] = mj;
#pragma unroll
    for (int s = 0; s < NS; s++)
      if (jR[s] == mj) { scR[s] = -1e30f; jR[s] = 0x7fffffff; }
  }

  const float m0 = wsv[0];
  float ex[8], sum = 0.f;
#pragma unroll
  for (int r = 0; r < 8; r++) { ex[r] = expf(wsv[r] - m0); sum += ex[r]; }
  const float inv = 1.f / sum;

  if (lane == 0) {
#pragma unroll
    for (int r = 0; r < 8; r++) {
      out_idx[(size_t)tok * 8 + r] = (float)wjv[r];
      out_w[(size_t)tok * 8 + r] = ex[r] * inv;
    }
  }
}

// ---------------------------------------------------------------------------
// K2g: V-gather. One wave per token.
// ---------------------------------------------------------------------------
__global__ __launch_bounds__(256) void k2g_gather(
    const float* __restrict__ V, const float* __restrict__ out_idx,
    const float* __restrict__ out_w, float* __restrict__ out) {
  const int tid = threadIdx.x;
  const int wv = tid >> 6, lane = tid & 63;
  const int tok = blockIdx.x * 4 + wv;    // 0..8191

  int jv[8]; float wv8[8];
#pragma unroll
  for (int r = 0; r < 8; r++) {
    jv[r] = ((int)out_idx[(size_t)tok * 8 + r]) & (NKNOW - 1);
    wv8[r] = out_w[(size_t)tok * 8 + r];
  }

  f32x4 a0 = {0.f,0.f,0.f,0.f}, a1 = a0, a2 = a0, a3 = a0;
#pragma unroll
  for (int r = 0; r < 8; r++) {
    const float w = wv8[r];
    const float* vp = V + (size_t)jv[r] * 1024 + lane * 16;
    const f32x4 v0 = *(const f32x4*)(vp);
    const f32x4 v1 = *(const f32x4*)(vp + 4);
    const f32x4 v2 = *(const f32x4*)(vp + 8);
    const f32x4 v3 = *(const f32x4*)(vp + 12);
    a0 += w * v0; a1 += w * v1; a2 += w * v2; a3 += w * v3;
  }
  float* op = out + (size_t)tok * 1024 + lane * 16;
  *(f32x4*)(op)      = a0;
  *(f32x4*)(op + 4)  = a1;
  *(f32x4*)(op + 8)  = a2;
  *(f32x4*)(op + 12) = a3;
}

// ---------------------------------------------------------------------------
extern "C" void kernel_launch(void* const* d_in, const int* in_sizes, int n_in,
                              void* d_out, int out_size, void* d_ws, size_t ws_size,
                              hipStream_t stream) {
  const float* x  = (const float*)d_in[0];   // [2,4096,1024]
  const float* mw = (const float*)d_in[1];   // [2,4096,16]
  const float* cn = (const float*)d_in[2];   // [16,1024,64]
  const float* kK = (const float*)d_in[3];   // [16384,64]
  const float* kV = (const float*)d_in[4];   // [16384,1024]

  float* out  = (float*)d_out;               // 8192*1024
  float* oidx = out + (size_t)NTOK * D_MODEL;       // 8192*8
  float* ow   = oidx + (size_t)NTOK * TOPK;         // 8192*8

  // Workspace (43 MB, well under the 72.35 MB proven in R5):
  //  [0,32M)      T (k1m3 out, k1b in); GM overlays after k1b.
  //  [32M,34M)    Qf   [34M,35M) Qb   [35M,37M) Kb
  //  [37M,39M)    Bh   [39M,41M) Bm   [41M,43M) Bl
  float* T   = (float*)d_ws;
  us* GM     = (us*)d_ws;
  float* Qf  = (float*)((char*)d_ws + 33554432);
  us* Qb     = (us*)((char*)d_ws + 35651584);
  us* Kb     = (us*)((char*)d_ws + 36700160);
  us* Bh     = (us*)((char*)d_ws + 38797312);
  us* Bm     = (us*)((char*)d_ws + 40894464);
  us* Bl     = (us*)((char*)d_ws + 42991616);

  k1cb3<<<1280, 256, 0, stream>>>(cn, Bh, Bm, Bl, kK, Kb);
  k1m3<<<512, 256, 0, stream>>>(x, Bh, Bm, Bl, T);
  k1b_weight<<<2048, 256, 0, stream>>>(T, mw, Qf, Qb);
  k2s_screen<<<1024, 256, 0, stream>>>(Qb, Kb, GM);
  k2b_sel<<<2048, 256, 0, stream>>>(Qf, kK, GM, oidx, ow);
  k2g_gather<<<2048, 256, 0, stream>>>(kV, oidx, ow, out);

  (void)in_sizes; (void)n_in; (void)out_size; (void)ws_size;
}

// Round 17
// 294.161 us; speedup vs baseline: 1.3228x; 1.0242x over previous
//
#include <hip/hip_runtime.h>
#include <hip/hip_bf16.h>

#define D_MODEL 1024
#define RANK 64
#define NCOMP 16
#define NKNOW 16384
#define TOPK 8
#define NTOK 8192   // B*S
#define MAXG 48     // candidate-group cap per token (groups of 8 j's)
#define NS 6        // rescore slots per lane (MAXG*8/64)

typedef __attribute__((ext_vector_type(4))) float f32x4;
typedef __attribute__((ext_vector_type(8))) short s16x8;
typedef unsigned short us;

static __device__ __forceinline__ us f2bf(float f) {
  union { float f; unsigned u; } v; v.f = f;
  unsigned r = v.u + 0x7FFFu + ((v.u >> 16) & 1u);
  return (us)(r >> 16);
}
static __device__ __forceinline__ float bf2f(us h) {
  union { unsigned u; float f; } v; v.u = ((unsigned)h) << 16;
  return v.f;
}

// async global->LDS, 16B per lane; LDS dest = wave-uniform base + lane*16.
#define GLOAD16(g, l)                                                        \
  __builtin_amdgcn_global_load_lds(                                          \
      (const __attribute__((address_space(1))) void*)(g),                    \
      (__attribute__((address_space(3))) void*)(l), 16, 0, 0)

// RNE 3-way split: x = h + m + l + r, |r| <= 2^-24 |x|.
#define SPLIT3(f, h, m, l)                                                   \
  do {                                                                       \
    h = f2bf(f);                                                             \
    const float r1_ = (f) - bf2f(h);                                         \
    m = f2bf(r1_);                                                           \
    const float r2_ = r1_ - bf2f(m);                                         \
    l = f2bf(r2_);                                                           \
  } while (0)

// ---------------------------------------------------------------------------
// K1cb3: transpose + 3-way RNE-split CN -> Bh,Bm,Bl [1024 c][1024 d],
// Bt[c][d] = cn[c>>6][d][c&63]. Structure proven in R6 (k1cb).
// ---------------------------------------------------------------------------
__global__ __launch_bounds__(256) void k1cb3(const float* __restrict__ CN,
                                             us* __restrict__ Bh,
                                             us* __restrict__ Bm,
                                             us* __restrict__ Bl) {
  __shared__ float tile[64][65];
  const int n = blockIdx.x >> 4, dt = blockIdx.x & 15;
  const int tid = threadIdx.x;
  {
    const int d = tid >> 2, rc = (tid & 3) * 16;
    const float* p = CN + ((size_t)n * 1024 + dt * 64 + d) * 64 + rc;
#pragma unroll
    for (int e = 0; e < 16; e += 4) {
      const f32x4 v = *(const f32x4*)(p + e);
      tile[d][rc + e]     = v[0];
      tile[d][rc + e + 1] = v[1];
      tile[d][rc + e + 2] = v[2];
      tile[d][rc + e + 3] = v[3];
    }
  }
  __syncthreads();
  {
    const int r = tid >> 2, dc = (tid & 3) * 16;
    s16x8 oh[2], om[2], ol[2];
#pragma unroll
    for (int g = 0; g < 2; g++)
#pragma unroll
      for (int e = 0; e < 8; e++) {
        const float v = tile[dc + g * 8 + e][r];
        us h, m, l;
        SPLIT3(v, h, m, l);
        oh[g][e] = (short)h; om[g][e] = (short)m; ol[g][e] = (short)l;
      }
    const size_t base = (size_t)(n * 64 + r) * 1024 + dt * 64 + dc;
#pragma unroll
    for (int g = 0; g < 2; g++) {
      *(s16x8*)(Bh + base + g * 8) = oh[g];
      *(s16x8*)(Bm + base + g * 8) = om[g];
      *(s16x8*)(Bl + base + g * 8) = ol[g];
    }
  }
}

// ---------------------------------------------------------------------------
// K1m3: T = Xh@Bh + [corrections] with SPLIT ACCUMULATORS (R12-proven,
// byte-identical). 128x128 tile, 4 waves, BK=32, grid 512.
// ---------------------------------------------------------------------------
__global__ __launch_bounds__(256) void k1m3(const float* __restrict__ X,
                                            const us* __restrict__ Bh,
                                            const us* __restrict__ Bm,
                                            const us* __restrict__ Bl,
                                            float* __restrict__ T) {
  __shared__ us As[3][4][128][8];      // 24 KB [split][kq][row][8]
  __shared__ us Bs[2][3][4][128][8];   // 48 KB [buf][split][kq][col][8]
  const int tid = threadIdx.x;
  const int w = tid >> 6, lane = tid & 63;
  const int wr = w >> 1, wc = w & 1;
  const int l15 = lane & 15, kq = lane >> 4;
  const int by = blockIdx.x >> 3, bx = blockIdx.x & 7;
  const int row0 = by * 128, col0 = bx * 128;

  const int sr = tid & 127, sh = tid >> 7;
  const float* xp = X + (size_t)(row0 + sr) * 1024 + sh * 16;

  const us* bsrc0[3]; const us* bsrc1[3];
  int bs_s[3], bs_q[3];
#pragma unroll
  for (int i = 0; i < 3; i++) {
    const int p = w * 3 + i;
    const int s = p >> 2, q = p & 3;
    bs_s[i] = s; bs_q[i] = q;
    const us* base = (s == 0) ? Bh : (s == 1) ? Bm : Bl;
    bsrc0[i] = base + (size_t)(col0 + lane) * 1024 + q * 8;
    bsrc1[i] = base + (size_t)(col0 + 64 + lane) * 1024 + q * 8;
  }

  f32x4 accH[4][4] = {};   // hh product only
  f32x4 accC[4][4] = {};   // correction products
  f32x4 xr[4];
  s16x8 creg[6];

#pragma unroll
  for (int i = 0; i < 3; i++) {
    GLOAD16(bsrc0[i], &Bs[0][bs_s[i]][bs_q[i]][0][0]);
    GLOAD16(bsrc1[i], &Bs[0][bs_s[i]][bs_q[i]][64][0]);
  }
#pragma unroll
  for (int g = 0; g < 4; g++) xr[g] = *(const f32x4*)(xp + g * 4);
#pragma unroll
  for (int g = 0; g < 4; g++)
#pragma unroll
    for (int e = 0; e < 4; e++) {
      us h, m, l;
      SPLIT3(xr[g][e], h, m, l);
      const int c = (g * 4 + e) >> 3, e8 = (g * 4 + e) & 7;
      creg[c][e8] = (short)h; creg[2 + c][e8] = (short)m; creg[4 + c][e8] = (short)l;
    }

  for (int kk = 0; kk < 32; ++kk) {
    const int cur = kk & 1;
    *(s16x8*)&As[0][sh * 2][sr][0]     = creg[0];
    *(s16x8*)&As[0][sh * 2 + 1][sr][0] = creg[1];
    *(s16x8*)&As[1][sh * 2][sr][0]     = creg[2];
    *(s16x8*)&As[1][sh * 2 + 1][sr][0] = creg[3];
    *(s16x8*)&As[2][sh * 2][sr][0]     = creg[4];
    *(s16x8*)&As[2][sh * 2 + 1][sr][0] = creg[5];
    __syncthreads();   // drains B gloads for kk (vmcnt 0) + As writes

    if (kk + 1 < 32) {
      const int ko = (kk + 1) * 32;
#pragma unroll
      for (int i = 0; i < 3; i++) {
        GLOAD16(bsrc0[i] + ko, &Bs[cur ^ 1][bs_s[i]][bs_q[i]][0][0]);
        GLOAD16(bsrc1[i] + ko, &Bs[cur ^ 1][bs_s[i]][bs_q[i]][64][0]);
      }
#pragma unroll
      for (int g = 0; g < 4; g++) xr[g] = *(const f32x4*)(xp + ko + g * 4);
    }

#define PROD(sa, sb, ACC)                                                     \
    do {                                                                      \
      s16x8 af[4];                                                            \
      _Pragma("unroll")                                                       \
      for (int mm = 0; mm < 4; mm++)                                          \
        af[mm] = *(const s16x8*)&As[sa][kq][wr * 64 + mm * 16 + l15][0];      \
      _Pragma("unroll")                                                       \
      for (int nn = 0; nn < 4; nn++) {                                        \
        const s16x8 bfr =                                                     \
            *(const s16x8*)&Bs[cur][sb][kq][wc * 64 + nn * 16 + l15][0];      \
        _Pragma("unroll")                                                     \
        for (int mm = 0; mm < 4; mm++)                                        \
          ACC[mm][nn] = __builtin_amdgcn_mfma_f32_16x16x32_bf16(              \
              af[mm], bfr, ACC[mm][nn], 0, 0, 0);                             \
      }                                                                       \
    } while (0)

    PROD(0, 0, accH);
    PROD(0, 1, accC); PROD(1, 0, accC); PROD(0, 2, accC);
    PROD(2, 0, accC); PROD(1, 1, accC);
#undef PROD

    if (kk + 1 < 32) {
#pragma unroll
      for (int g = 0; g < 4; g++)
#pragma unroll
        for (int e = 0; e < 4; e++) {
          us h, m, l;
          SPLIT3(xr[g][e], h, m, l);
          const int c = (g * 4 + e) >> 3, e8 = (g * 4 + e) & 7;
          creg[c][e8] = (short)h; creg[2 + c][e8] = (short)m;
          creg[4 + c][e8] = (short)l;
        }
    }
    __syncthreads();   // all waves done reading As/Bs[cur]
  }

#pragma unroll
  for (int mm = 0; mm < 4; mm++)
#pragma unroll
    for (int nn = 0; nn < 4; nn++)
#pragma unroll
      for (int r = 0; r < 4; r++)
        T[(size_t)(row0 + wr * 64 + mm * 16 + kq * 4 + r) * 1024
          + col0 + wc * 64 + nn * 16 + l15] = accH[mm][nn][r] + accC[mm][nn][r];
}

// ---------------------------------------------------------------------------
// K1b: Q[tok][r] = sum_n mw[tok][n] * T[tok][n*64+r]; also emit bf16 copy.
// ---------------------------------------------------------------------------
__global__ __launch_bounds__(256) void k1b_weight(const float* __restrict__ T,
                                                  const float* __restrict__ MW,
                                                  float* __restrict__ Qf,
                                                  us* __restrict__ Qb) {
  const int gid = blockIdx.x * 256 + threadIdx.x;  // 0..524287
  const int tok = gid >> 6, r = gid & 63;
  float q = 0.f;
#pragma unroll
  for (int n = 0; n < 16; n++)
    q = fmaf(MW[tok * 16 + n], T[(size_t)tok * 1024 + n * 64 + r], q);
  Qf[gid] = q;
  Qb[gid] = f2bf(q);
}

// ---------------------------------------------------------------------------
// K1c: Kb = bf16(knowledge_K)
// ---------------------------------------------------------------------------
__global__ __launch_bounds__(256) void k1c_cvt(const float* __restrict__ Kf,
                                               us* __restrict__ Kb) {
  const int gid = blockIdx.x * 256 + threadIdx.x;  // one per 4 elems
  f32x4 v = *(const f32x4*)(Kf + (size_t)gid * 4);
  us o0 = f2bf(v[0]), o1 = f2bf(v[1]), o2 = f2bf(v[2]), o3 = f2bf(v[3]);
  unsigned long long pack = (unsigned long long)o0 | ((unsigned long long)o1 << 16)
                          | ((unsigned long long)o2 << 32) | ((unsigned long long)o3 << 48);
  *(unsigned long long*)(Kb + (size_t)gid * 4) = pack;
}

// ---------------------------------------------------------------------------
// K2s v2: screening with TWO token-groups per wave. Each af (Kb fragment) is
// loaded once and feeds 2 B-fragments (4 MFMAs, 2 independent acc chains) ->
// Kb L2 traffic halves and wave count halves. GM values bit-identical to v1.
// grid 1024; wave gw=(blk*4+wv): tg=gw>>4 (32 tokens, tb=tg*32), jsl=gw&15.
// ---------------------------------------------------------------------------
__global__ __launch_bounds__(256) void k2s_screen(
    const us* __restrict__ Qb, const us* __restrict__ Kb,
    us* __restrict__ GM) {
  __shared__ us sh[4][32][136];   // 34.8 KB
  const int tid = threadIdx.x;
  const int wv = tid >> 6, lane = tid & 63;
  const int gw = blockIdx.x * 4 + wv;     // 0..4095
  const int tg = gw >> 4;                 // token group 0..255 (32 tokens)
  const int jsl = gw & 15;                // j-slice 0..15
  const int tb = tg * 32;
  const int myTok = lane & 15;
  const int slice = lane >> 4;            // 0..3

  const s16x8 bfa0 = *(const s16x8*)(Qb + (size_t)(tb + myTok) * 64 + slice * 8);
  const s16x8 bfa1 = *(const s16x8*)(Qb + (size_t)(tb + myTok) * 64 + 32 + slice * 8);
  const s16x8 bfb0 = *(const s16x8*)(Qb + (size_t)(tb + 16 + myTok) * 64 + slice * 8);
  const s16x8 bfb1 = *(const s16x8*)(Qb + (size_t)(tb + 16 + myTok) * 64 + 32 + slice * 8);

  const int j0 = jsl * 1024;
  const us* ap0 = Kb + (size_t)(j0 + myTok) * 64 + slice * 8;
  s16x8 af0 = *(const s16x8*)(ap0);
  s16x8 af1 = *(const s16x8*)(ap0 + 32);
  const bool writer = (slice & 1) == 0;
  const int sub = slice >> 1;

  for (int tt = 0; tt < 64; ++tt) {
    f32x4 ca = {0.f, 0.f, 0.f, 0.f};
    f32x4 cb = {0.f, 0.f, 0.f, 0.f};
    ca = __builtin_amdgcn_mfma_f32_16x16x32_bf16(af0, bfa0, ca, 0, 0, 0);
    cb = __builtin_amdgcn_mfma_f32_16x16x32_bf16(af0, bfb0, cb, 0, 0, 0);
    ca = __builtin_amdgcn_mfma_f32_16x16x32_bf16(af1, bfa1, ca, 0, 0, 0);
    cb = __builtin_amdgcn_mfma_f32_16x16x32_bf16(af1, bfb1, cb, 0, 0, 0);
    if (tt + 1 < 64) {
      const us* ap = ap0 + (size_t)(tt + 1) * 16 * 64;
      af0 = *(const s16x8*)(ap);
      af1 = *(const s16x8*)(ap + 32);
    }
    const float gma4 = fmaxf(fmaxf(ca[0], ca[1]), fmaxf(ca[2], ca[3]));
    const float gma8 = fmaxf(gma4, __shfl_xor(gma4, 16));
    const float gmb4 = fmaxf(fmaxf(cb[0], cb[1]), fmaxf(cb[2], cb[3]));
    const float gmb8 = fmaxf(gmb4, __shfl_xor(gmb4, 16));
    if (writer) {
      sh[wv][myTok][2 * tt + sub] = f2bf(gma8);
      sh[wv][16 + myTok][2 * tt + sub] = f2bf(gmb8);
    }
  }
  __syncthreads();
  // coalesced write: lane -> (token = lane>>1, half = lane&1), 8 x 16B chunks
  {
    const int t = lane >> 1;
    const int half = (lane & 1) * 64;
    us* orow = GM + (size_t)(tb + t) * 2048 + jsl * 128 + half;
#pragma unroll
    for (int ch = 0; ch < 8; ch++)
      *(s16x8*)(orow + ch * 8) = *(const s16x8*)&sh[wv][t][half + ch * 8];
  }
}

// ---------------------------------------------------------------------------
// K2b: one wave per token. 2048 group-maxima -> thr = 8th-largest lane-max -
// margin -> compact groups -> exact f32 rescore -> exact top-8 (desc score,
// asc idx) -> softmax -> gather V -> outputs. V-gather index masked to
// [0,NKNOW) so a sentinel can never fault (no effect on correct runs).
// ---------------------------------------------------------------------------
__global__ __launch_bounds__(256) void k2b_select(
    const float* __restrict__ Qf, const float* __restrict__ Kf,
    const float* __restrict__ V, const us* __restrict__ GM,
    float* __restrict__ out, float* __restrict__ out_idx,
    float* __restrict__ out_w) {
  __shared__ float qsh[4][64];
  __shared__ int csh[4][MAXG];
  __shared__ int scnt[4];
  const int tid = threadIdx.x;
  const int wv = tid >> 6, lane = tid & 63;
  const int tok = blockIdx.x * 4 + wv;    // 0..8191

  if (lane == 0) scnt[wv] = 0;
  qsh[wv][lane] = Qf[(size_t)tok * 64 + lane];

  unsigned long long gv[8];
  const unsigned long long* gmp =
      (const unsigned long long*)(GM + (size_t)tok * 2048);
#pragma unroll
  for (int i = 0; i < 8; i++) gv[i] = gmp[i * 64 + lane];

  float lm = -1e30f;
#pragma unroll
  for (int i = 0; i < 8; i++)
#pragma unroll
    for (int e = 0; e < 4; e++)
      lm = fmaxf(lm, bf2f((us)(gv[i] >> (e * 16))));

  float v = lm, m8 = -1e30f;
#pragma unroll
  for (int e = 0; e < 8; e++) {
    float m = v;
#pragma unroll
    for (int d = 1; d < 64; d <<= 1) m = fmaxf(m, __shfl_xor(m, d));
    m8 = m;
    if (e < 7) v = (v == m) ? -1e30f : v;
  }
  const float thr = m8 - 0.04f;

#pragma unroll
  for (int i = 0; i < 8; i++) {
#pragma unroll
    for (int e = 0; e < 4; e++) {
      const float g = bf2f((us)(gv[i] >> (e * 16)));
      if (g >= thr) {
        const int s = atomicAdd(&scnt[wv], 1);
        if (s < MAXG) csh[wv][s] = i * 256 + lane * 4 + e;
      }
    }
  }
  int ng = scnt[wv];
  if (ng > MAXG) ng = MAXG;
  const int nj = ng * 8;

  float scR[NS]; int jR[NS];
#pragma unroll
  for (int s = 0; s < NS; s++) {
    scR[s] = -1e30f; jR[s] = 0x7fffffff;
    if (s * 64 < nj) {
      const int ci = s * 64 + lane;
      if (ci < nj) {
        const int j = csh[wv][ci >> 3] * 8 + (ci & 7);
        const float* kp = Kf + (size_t)j * 64;
        float acc = 0.f;
#pragma unroll
        for (int k = 0; k < 64; k += 4) {
          const f32x4 qv = *(const f32x4*)&qsh[wv][k];
          const f32x4 kv = *(const f32x4*)(kp + k);
          acc = fmaf(qv[0], kv[0], acc);
          acc = fmaf(qv[1], kv[1], acc);
          acc = fmaf(qv[2], kv[2], acc);
          acc = fmaf(qv[3], kv[3], acc);
        }
        scR[s] = acc * 0.125f; jR[s] = j;
      }
    }
  }

  float wsv[8]; int wjv[8];
#pragma unroll
  for (int e = 0; e < 8; e++) {
    float ms = scR[0]; int mj = jR[0];
#pragma unroll
    for (int s = 1; s < NS; s++)
      if (scR[s] > ms || (scR[s] == ms && jR[s] < mj)) { ms = scR[s]; mj = jR[s]; }
#pragma unroll
    for (int d = 1; d < 64; d <<= 1) {
      const float rs = __shfl_xor(ms, d);
      const int rj = __shfl_xor(mj, d);
      if (rs > ms || (rs == ms && rj < mj)) { ms = rs; mj = rj; }
    }
    wsv[e] = ms; wjv[e] = mj;
#pragma unroll
    for (int s = 0; s < NS; s++)
      if (jR[s] == mj) { scR[s] = -1e30f; jR[s] = 0x7fffffff; }
  }

  const float m0 = wsv[0];
  float ex[8], sum = 0.f;
#pragma unroll
  for (int r = 0; r < 8; r++) { ex[r] = expf(wsv[r] - m0); sum += ex[r]; }
  const float inv = 1.f / sum;

  if (lane == 0) {
#pragma unroll
    for (int r = 0; r < 8; r++) {
      out_idx[(size_t)tok * 8 + r] = (float)wjv[r];
      out_w[(size_t)tok * 8 + r] = ex[r] * inv;
    }
  }

  f32x4 a0 = {0.f,0.f,0.f,0.f}, a1 = a0, a2 = a0, a3 = a0;
#pragma unroll
  for (int r = 0; r < 8; r++) {
    const float w = ex[r] * inv;
    const float* vp = V + (size_t)(wjv[r] & (NKNOW - 1)) * 1024 + lane * 16;
    const f32x4 v0 = *(const f32x4*)(vp);
    const f32x4 v1 = *(const f32x4*)(vp + 4);
    const f32x4 v2 = *(const f32x4*)(vp + 8);
    const f32x4 v3 = *(const f32x4*)(vp + 12);
    a0 += w * v0; a1 += w * v1; a2 += w * v2; a3 += w * v3;
  }
  float* op = out + (size_t)tok * 1024 + lane * 16;
  *(f32x4*)(op)      = a0;
  *(f32x4*)(op + 4)  = a1;
  *(f32x4*)(op + 8)  = a2;
  *(f32x4*)(op + 12) = a3;
}

// ---------------------------------------------------------------------------
extern "C" void kernel_launch(void* const* d_in, const int* in_sizes, int n_in,
                              void* d_out, int out_size, void* d_ws, size_t ws_size,
                              hipStream_t stream) {
  const float* x  = (const float*)d_in[0];   // [2,4096,1024]
  const float* mw = (const float*)d_in[1];   // [2,4096,16]
  const float* cn = (const float*)d_in[2];   // [16,1024,64]
  const float* kK = (const float*)d_in[3];   // [16384,64]
  const float* kV = (const float*)d_in[4];   // [16384,1024]

  float* out  = (float*)d_out;               // 8192*1024
  float* oidx = out + (size_t)NTOK * D_MODEL;       // 8192*8
  float* ow   = oidx + (size_t)NTOK * TOPK;         // 8192*8

  // Workspace (43 MB, well under the 72.35 MB proven in R5):
  //  [0,32M)      T (k1m3 out, k1b in); GM overlays after k1b.
  //  [32M,34M)    Qf   [34M,35M) Qb   [35M,37M) Kb
  //  [37M,39M)    Bh   [39M,41M) Bm   [41M,43M) Bl
  float* T   = (float*)d_ws;
  us* GM     = (us*)d_ws;
  float* Qf  = (float*)((char*)d_ws + 33554432);
  us* Qb     = (us*)((char*)d_ws + 35651584);
  us* Kb     = (us*)((char*)d_ws + 36700160);
  us* Bh     = (us*)((char*)d_ws + 38797312);
  us* Bm     = (us*)((char*)d_ws + 40894464);
  us* Bl     = (us*)((char*)d_ws + 42991616);

  k1cb3<<<256, 256, 0, stream>>>(cn, Bh, Bm, Bl);
  k1m3<<<512, 256, 0, stream>>>(x, Bh, Bm, Bl, T);
  k1b_weight<<<2048, 256, 0, stream>>>(T, mw, Qf, Qb);
  k1c_cvt<<<1024, 256, 0, stream>>>(kK, Kb);
  k2s_screen<<<1024, 256, 0, stream>>>(Qb, Kb, GM);
  k2b_select<<<2048, 256, 0, stream>>>(Qf, kK, kV, GM, out, oidx, ow);

  (void)in_sizes; (void)n_in; (void)out_size; (void)ws_size;
}